// Round 15
// baseline (309.574 us; speedup 1.0000x reference)
//
#include <hip/hip_runtime.h>

#define N_ENT 100000
#define N_HE  20000
#define DD    128

// Unified x-space rows: ego 0..100000, h1 100000..120000, h2 120000..140000
#define XROW_H1 100000
#define XROW_H2 120000

// rp row spaces
#define RP_S2  0
#define RP_P1  100001
#define RP_L1  120002

// Bucket geometry:
// region 0 = S2 (A+P2+L2 merged): 196 buckets, stride 512, cap 19968
// region 1 = P1: 79 buckets, stride 256, cap 13824
// region 2 = L1: 79 buckets, stride 256, cap 13824
#define NB 354
#define TILE 3072
#define EPT  12   // entries per thread = TILE/256

typedef float f32x4 __attribute__((ext_vector_type(4)));
typedef short bf16x8 __attribute__((ext_vector_type(8)));

__device__ __forceinline__ int bucket_region(int b) {
    return (b < 196) ? 0 : (b < 275) ? 1 : 2;
}
__device__ __forceinline__ int reg_shift(int r)      { return r == 0 ? 9 : 8; }
__device__ __forceinline__ int reg_bucketbase(int r) { return r == 0 ? 0 : r == 1 ? 196 : 275; }
__device__ __forceinline__ int reg_cap(int r)        { return r == 0 ? 19968 : 13824; }
__device__ __forceinline__ long long reg_arenabase(int r) {
    return r == 0 ? 0LL : r == 1 ? 3913728LL : 5005824LL;   // 196*19968 ; +79*13824
}
__device__ __forceinline__ int reg_rpbase(int r)     { return r == 0 ? RP_S2 : r == 1 ? RP_P1 : RP_L1; }
__device__ __forceinline__ int reg_rows(int r)       { return r == 0 ? 100000 : 20000; }

__device__ __forceinline__ unsigned short f2bf(float f) {
    unsigned u = __float_as_uint(f);
    unsigned r = (u + 0x7fffu + ((u >> 16) & 1u)) >> 16;   // RNE
    return (unsigned short)r;
}
__device__ __forceinline__ unsigned pack_bf16(float a, float b) {
    return (unsigned)f2bf(a) | ((unsigned)f2bf(b) << 16);
}
__device__ __forceinline__ float lrelu(float x) { return x > 0.0f ? x : 0.01f * x; }
__device__ __forceinline__ float i8f(unsigned u, int b) {
    return (float)((int)(u << (24 - 8 * b)) >> 24);
}

// ---------------- ego fp32 -> block-scaled int8 rows of xall ----------------
__global__ __launch_bounds__(256) void quant_ego_kernel(
    const float* __restrict__ ego, unsigned* __restrict__ xq,
    float* __restrict__ xs)
{
    int row = (blockIdx.x * 256 + threadIdx.x) >> 5;
    if (row >= N_ENT) return;
    int l = threadIdx.x & 31;
    const float4 v = *(const float4*)(ego + (long long)row * DD + l * 4);
    float m = fmaxf(fmaxf(fabsf(v.x), fabsf(v.y)), fmaxf(fabsf(v.z), fabsf(v.w)));
    for (int d = 1; d < 32; d <<= 1) m = fmaxf(m, __shfl_xor(m, d, 32));
    float inv = (m > 0.0f) ? 127.0f / m : 0.0f;
    int q0 = __float2int_rn(v.x * inv);
    int q1 = __float2int_rn(v.y * inv);
    int q2 = __float2int_rn(v.z * inv);
    int q3 = __float2int_rn(v.w * inv);
    unsigned pk = (q0 & 255) | ((q1 & 255) << 8) | ((q2 & 255) << 16) | ((q3 & 255) << 24);
    xq[row * 32 + l] = pk;
    if (l == 0) xs[row] = m * (1.0f / 127.0f);
}

struct BuildArgs {
    const int*   rows[5];
    const int*   cols[5];
    const float* vals[5];
    int nnzbase[6];
};

// seg -> bucket mapping: {A,P1,P2,L1,L2}
__device__ __forceinline__ int seg_bbase(int s)  { return (s == 1) ? 196 : (s == 3) ? 275 : 0; }
__device__ __forceinline__ int seg_shift2(int s) { return (s == 1 || s == 3) ? 8 : 9; }
__device__ __forceinline__ int seg_colofs(int s) { return (s == 2) ? XROW_H1 : (s == 4) ? XROW_H2 : 0; }

__device__ __forceinline__ void seg_of(int i, const int* nnzbase, int& seg, int& li) {
    int s = 0;
    s += (i >= nnzbase[1]);
    s += (i >= nnzbase[2]);
    s += (i >= nnzbase[3]);
    s += (i >= nnzbase[4]);
    seg = s; li = i - nnzbase[s];
}

// ---------------- Phase A: LDS-binned partition into bucket arena ----------------
__global__ __launch_bounds__(256, 4) void partition_kernel(
    BuildArgs a, int* __restrict__ gcursor, int2* __restrict__ arena)
{
    __shared__ int2 staging[TILE];              // 24 KB
    __shared__ unsigned short posb[TILE];       // 6 KB
    __shared__ int  hist[NB];
    __shared__ int  excl[NB + 1];
    __shared__ int  cursor[NB];
    __shared__ int  gofs[NB];                   // gbase[b] - excl[b]

    const int t = threadIdx.x;
    const int tile_base = blockIdx.x * TILE;
    const int total = a.nnzbase[5];
    int tile_n = total - tile_base;
    if (tile_n > TILE) tile_n = TILE;
    if (tile_n <= 0) return;

    for (int i = t; i < NB; i += 256) hist[i] = 0;
    __syncthreads();

    // pass 1: read rows+cols+vals ONCE, histogram, cache everything in regs
    int   pk[EPT];
    int   pcol[EPT];
    float pval[EPT];
#pragma unroll
    for (int q = 0; q < EPT; ++q) {
        int j = t + q * 256;
        pk[q] = -1;
        if (j < tile_n) {
            int i = tile_base + j;
            int seg, li; seg_of(i, a.nnzbase, seg, li);
            int row = a.rows[seg][li];
            pcol[q] = a.cols[seg][li] + seg_colofs(seg);
            pval[q] = a.vals[seg][li];
            int sh = seg_shift2(seg);
            int b = seg_bbase(seg) + (row >> sh);
            pk[q] = (b << 9) | (row & ((1 << sh) - 1));
            atomicAdd(&hist[b], 1);
        }
    }
    __syncthreads();

    // wave 0: exclusive scan of hist -> excl
    if (t < 64) {
        int carry = 0;
        for (int base = 0; base < NB; base += 64) {
            int idx = base + t;
            int v = (idx < NB) ? hist[idx] : 0;
            int inc = v;
            for (int d = 1; d < 64; d <<= 1) {
                int u = __shfl_up(inc, d, 64);
                if (t >= d) inc += u;
            }
            if (idx < NB) excl[idx] = carry + inc - v;
            carry += __shfl(inc, 63, 64);
        }
        if (t == 0) excl[NB] = carry;
    }
    __syncthreads();

    // reserve global arena ranges; init cursors; fill posb (fused loop)
    for (int b = t; b < NB; b += 256) {
        int e  = excl[b];
        int hi = excl[b + 1];
        int c  = hi - e;
        int gb = (c > 0) ? atomicAdd(&gcursor[b], c) : 0;
        cursor[b] = e;
        gofs[b] = gb - e;
        for (int p = e; p < hi; ++p) posb[p] = (unsigned short)b;
    }
    __syncthreads();

    // pass 2: scatter from regs into LDS staging grouped by bucket
#pragma unroll
    for (int q = 0; q < EPT; ++q) {
        if (pk[q] >= 0) {
            int b  = pk[q] >> 9;
            int rl = pk[q] & 511;
            int pos = atomicAdd(&cursor[b], 1);
            staging[pos] = make_int2((rl << 18) | pcol[q], __float_as_int(pval[q]));
        }
    }
    __syncthreads();

    // flush: contiguous, position-ordered writes
    for (int p = t; p < tile_n; p += 256) {
        int b = posb[p];
        int reg = bucket_region(b);
        long long slot = reg_arenabase(reg) + (long long)(b - reg_bucketbase(reg)) * reg_cap(reg);
        arena[slot + gofs[b] + p] = staging[p];
    }
}

// ---------------- bucket-count exclusive scan (+rp sentinels) ----------------
__global__ __launch_bounds__(512) void bucket_scan_kernel(
    const int* __restrict__ gcursor, int* __restrict__ bbase, int* __restrict__ rp)
{
    __shared__ int tmp[512];
    int t = threadIdx.x;
    int v = (t < NB) ? gcursor[t] : 0;
    tmp[t] = v;
    __syncthreads();
    for (int d = 1; d < 512; d <<= 1) {
        int u = (t >= d) ? tmp[t - d] : 0;
        __syncthreads();
        tmp[t] += u;
        __syncthreads();
    }
    if (t < NB) bbase[t] = tmp[t] - v;
    // region sentinels
    if (t == 196) rp[RP_S2 + 100000] = tmp[t] - v;   // end of S2
    if (t == 275) rp[RP_P1 + 20000]  = tmp[t] - v;   // end of P1
    if (t == NB - 1) rp[RP_L1 + 20000] = tmp[t];     // total
}

// ---------------- Phase B: per-bucket counting sort -> final cv + rp ----------------
__global__ __launch_bounds__(256) void bucket_sort_kernel(
    const int* __restrict__ gcursor, const int* __restrict__ bbase,
    const int2* __restrict__ arena, int2* __restrict__ cv, int* __restrict__ rp)
{
    __shared__ int hist[512];
    __shared__ int excl[512];
    __shared__ int wsum[4];

    const int b = blockIdx.x;
    const int t = threadIdx.x;
    const int reg = bucket_region(b);
    const int sh = reg_shift(reg);
    const int stride = 1 << sh;
    const int lb = b - reg_bucketbase(reg);
    const int row_base_local = lb << sh;
    int nrows = reg_rows(reg) - row_base_local;
    if (nrows > stride) nrows = stride;
    const long long slot = reg_arenabase(reg) + (long long)lb * reg_cap(reg);
    const int count = gcursor[b];
    const int fbase = bbase[b];

    for (int i = t; i < 512; i += 256) hist[i] = 0;
    __syncthreads();

    for (int j = t; j < count; j += 256) {
        int key = arena[slot + j].x;
        atomicAdd(&hist[key >> 18], 1);
    }
    __syncthreads();

    // exclusive scan of 512 bins (2 per thread)
    {
        const int lane = t & 63, wave = t >> 6;
        int v0 = hist[t * 2], v1 = hist[t * 2 + 1];
        int s = v0 + v1;
        int inc = s;
        for (int d = 1; d < 64; d <<= 1) {
            int u = __shfl_up(inc, d, 64);
            if (lane >= d) inc += u;
        }
        if (lane == 63) wsum[wave] = inc;
        __syncthreads();
        int woff = 0;
        for (int w = 0; w < wave; ++w) woff += wsum[w];
        int run = woff + inc - s;
        excl[t * 2] = run;
        excl[t * 2 + 1] = run + v0;
    }
    __syncthreads();

    const int grow0 = reg_rpbase(reg) + row_base_local;
    for (int r = t; r < nrows; r += 256)
        rp[grow0 + r] = fbase + excl[r];
    __syncthreads();

    for (int j = t; j < count; j += 256) {
        int2 e = arena[slot + j];
        int r = e.x >> 18;
        int pos = atomicAdd(&excl[r], 1);
        cv[fbase + pos] = make_int2(e.x & 0x3FFFF, e.y);
    }
}

// ---------------- SpMM gather walk: group-of-8, depth-2 software pipeline ----------------
// Lane l: group g = l>>3 handles nnz; sublane s = l&7 loads 16 B of the row.
// Each iteration covers 16 nnz with TWO independent uint4 loads issued
// back-to-back (named regs, no runtime indexing) -> 2 gathers in flight/wave.
// Tail handled by index-clamp (duplicate line loads, vs=0).
__device__ __forceinline__ void walk_row8(
    const int2* __restrict__ cv, int start, int end, int lane,
    const unsigned* __restrict__ xq, const float* __restrict__ xs, float* acc)
{
    const int g  = lane >> 3;
    const int s4 = (lane & 7) * 4;

    for (int sb = start; sb < end; sb += 64) {
        int nn = end - sb; if (nn > 64) nn = 64;
        int2 mycv = make_int2(0, 0);
        float myv = 0.0f;
        if (lane < nn) {
            mycv = cv[sb + lane];
            myv = __int_as_float(mycv.y) * xs[mycv.x];
        }
        const int nn1 = nn - 1;
        for (int jb = 0; jb < nn; jb += 16) {
            int idx0 = jb + g;
            int idx1 = jb + 8 + g;
            int i0 = idx0 < nn1 ? idx0 : nn1;
            int i1 = idx1 < nn1 ? idx1 : nn1;
            int   cs0 = __shfl(mycv.x, i0, 64);
            int   cs1 = __shfl(mycv.x, i1, 64);
            float vs0 = __shfl(myv, i0, 64);
            float vs1 = __shfl(myv, i1, 64);
            vs0 = (idx0 <= nn1) ? vs0 : 0.0f;
            vs1 = (idx1 <= nn1) ? vs1 : 0.0f;
            // issue both loads before any compute
            const uint4 u0 = *reinterpret_cast<const uint4*>(xq + cs0 * 32 + s4);
            const uint4 u1 = *reinterpret_cast<const uint4*>(xq + cs1 * 32 + s4);
#pragma unroll
            for (int w = 0; w < 4; ++w) {
                unsigned uw = (&u0.x)[w];
                acc[w * 4 + 0] = fmaf(vs0, i8f(uw, 0), acc[w * 4 + 0]);
                acc[w * 4 + 1] = fmaf(vs0, i8f(uw, 1), acc[w * 4 + 1]);
                acc[w * 4 + 2] = fmaf(vs0, i8f(uw, 2), acc[w * 4 + 2]);
                acc[w * 4 + 3] = fmaf(vs0, i8f(uw, 3), acc[w * 4 + 3]);
            }
#pragma unroll
            for (int w = 0; w < 4; ++w) {
                unsigned uw = (&u1.x)[w];
                acc[w * 4 + 0] = fmaf(vs1, i8f(uw, 0), acc[w * 4 + 0]);
                acc[w * 4 + 1] = fmaf(vs1, i8f(uw, 1), acc[w * 4 + 1]);
                acc[w * 4 + 2] = fmaf(vs1, i8f(uw, 2), acc[w * 4 + 2]);
                acc[w * 4 + 3] = fmaf(vs1, i8f(uw, 3), acc[w * 4 + 3]);
            }
        }
    }
}

__device__ __forceinline__ void reduce_groups8(float* acc)
{
#pragma unroll
    for (int e = 0; e < 16; ++e) {
        acc[e] += __shfl_xor(acc[e], 8, 64);
        acc[e] += __shfl_xor(acc[e], 16, 64);
        acc[e] += __shfl_xor(acc[e], 32, 64);
    }
}

// stage 1: h1 = p1 @ ego, h2 = l1 @ ego  (int8 gather -> int8 block-scaled rows of xall)
__global__ __launch_bounds__(256) void spmm_stage1_kernel(
    const int* __restrict__ rp, const int2* __restrict__ cv,
    unsigned* __restrict__ xq, float* __restrict__ xs)
{
    int wid = (blockIdx.x * 256 + threadIdx.x) >> 6;
    int lane = threadIdx.x & 63;
    if (wid >= 2 * N_HE) return;
    int rbase, xrow;
    if (wid < N_HE) { rbase = RP_P1 + wid;           xrow = XROW_H1 + wid; }
    else            { rbase = RP_L1 + (wid - N_HE);  xrow = XROW_H2 + (wid - N_HE); }

    float acc[16];
#pragma unroll
    for (int e = 0; e < 16; ++e) acc[e] = 0.0f;
    walk_row8(cv, rp[rbase], rp[rbase + 1], lane, xq, xs, acc);
    reduce_groups8(acc);

    float m = 0.0f;
#pragma unroll
    for (int e = 0; e < 16; ++e) m = fmaxf(m, fabsf(acc[e]));
    m = fmaxf(m, __shfl_xor(m, 1, 64));
    m = fmaxf(m, __shfl_xor(m, 2, 64));
    m = fmaxf(m, __shfl_xor(m, 4, 64));
    float inv = (m > 0.0f) ? 127.0f / m : 0.0f;

    if (lane < 8) {
        uint4 o;
#pragma unroll
        for (int w = 0; w < 4; ++w) {
            int q0 = __float2int_rn(acc[w * 4 + 0] * inv);
            int q1 = __float2int_rn(acc[w * 4 + 1] * inv);
            int q2 = __float2int_rn(acc[w * 4 + 2] * inv);
            int q3 = __float2int_rn(acc[w * 4 + 3] * inv);
            (&o.x)[w] = (q0 & 255) | ((q1 & 255) << 8) | ((q2 & 255) << 16) | ((q3 & 255) << 24);
        }
        *reinterpret_cast<uint4*>(xq + xrow * 32 + lane * 4) = o;
        if (lane == 0) xs[xrow] = m * (1.0f / 127.0f);
    }
}

// stage 2: side = (A|p2|l2) @ xall  — ONE merged walk per output row
__global__ __launch_bounds__(256) void spmm_stage2_kernel(
    const int* __restrict__ rp, const int2* __restrict__ cv,
    const unsigned* __restrict__ xq, const float* __restrict__ xs,
    float* __restrict__ side)
{
    int wid = (blockIdx.x * 256 + threadIdx.x) >> 6;
    int lane = threadIdx.x & 63;
    if (wid >= N_ENT) return;

    float acc[16];
#pragma unroll
    for (int e = 0; e < 16; ++e) acc[e] = 0.0f;
    walk_row8(cv, rp[wid], rp[wid + 1], lane, xq, xs, acc);
    reduce_groups8(acc);

    if (lane < 8) {
        float* yp = side + (long long)wid * DD + lane * 16;
#pragma unroll
        for (int w = 0; w < 4; ++w)
            *reinterpret_cast<float4*>(yp + w * 4) =
                make_float4(acc[w * 4], acc[w * 4 + 1], acc[w * 4 + 2], acc[w * 4 + 3]);
    }
}

// ---------------- MFMA dense epilogue (512 threads, 16 rows/wave) ----------------
union BfFrag { unsigned u[4]; bf16x8 v; };

__global__ __launch_bounds__(512, 4) void dense_mfma_kernel(
    const float* __restrict__ ego, const float* __restrict__ side,
    const float* __restrict__ W1, const float* __restrict__ b1,
    const float* __restrict__ W2, const float* __restrict__ b2,
    float* __restrict__ out)
{
    __shared__ unsigned Wb1[8192];   // 32 KB: W1 bf16, swizzled
    __shared__ unsigned Wb2[8192];   // 32 KB: W2 bf16, swizzled

    const int tid = threadIdx.x;

    for (int idx = tid; idx < 8192; idx += 512) {
        int row = idx >> 6, pc = idx & 63;
        unsigned pk1 = pack_bf16(W1[row * 128 + pc * 2], W1[row * 128 + pc * 2 + 1]);
        unsigned pk2 = pack_bf16(W2[row * 128 + pc * 2], W2[row * 128 + pc * 2 + 1]);
        int boff = row * 256 + ((pc * 4) ^ ((row & 7) << 4));
        *(unsigned*)((char*)Wb1 + boff) = pk1;
        *(unsigned*)((char*)Wb2 + boff) = pk2;
    }
    __syncthreads();

    const int wave = tid >> 6;   // 0..7
    const int lane = tid & 63;
    const int m    = lane & 15;
    const int kg   = lane >> 4;

    float bs[8], bb[8];
#pragma unroll
    for (int c = 0; c < 8; ++c) {
        bs[c] = b1[c * 16 + m];
        bb[c] = b2[c * 16 + m];
    }

    for (int wt = blockIdx.x * 8 + wave; wt < 6250; wt += gridDim.x * 8) {
        const long long r0 = (long long)(wt * 16 + m) * DD;

        f32x4 accS[8], accB[8];
#pragma unroll
        for (int c = 0; c < 8; ++c) { accS[c] = (f32x4)0.0f; accB[c] = (f32x4)0.0f; }

#pragma unroll 1
        for (int kk = 0; kk < 4; ++kk) {
            const int kb = kk * 32 + kg * 8;

            float4 ea = *(const float4*)(ego  + r0 + kb);
            float4 eb = *(const float4*)(ego  + r0 + kb + 4);
            float4 sa = *(const float4*)(side + r0 + kb);
            float4 sb = *(const float4*)(side + r0 + kb + 4);

            BfFrag aS, aB;
            aS.u[0] = pack_bf16(ea.x + sa.x, ea.y + sa.y);
            aS.u[1] = pack_bf16(ea.z + sa.z, ea.w + sa.w);
            aS.u[2] = pack_bf16(eb.x + sb.x, eb.y + sb.y);
            aS.u[3] = pack_bf16(eb.z + sb.z, eb.w + sb.w);
            aB.u[0] = pack_bf16(ea.x * sa.x, ea.y * sa.y);
            aB.u[1] = pack_bf16(ea.z * sa.z, ea.w * sa.w);
            aB.u[2] = pack_bf16(eb.x * sb.x, eb.y * sb.y);
            aB.u[3] = pack_bf16(eb.z * sb.z, eb.w * sb.w);

#pragma unroll
            for (int c = 0; c < 8; ++c) {
                int wrow = c * 16 + m;
                int boff = wrow * 256 + ((kk * 64 + (kg << 4)) ^ ((wrow & 7) << 4));
                bf16x8 w1 = *(const bf16x8*)((const char*)Wb1 + boff);
                bf16x8 w2 = *(const bf16x8*)((const char*)Wb2 + boff);
                accS[c] = __builtin_amdgcn_mfma_f32_16x16x32_bf16(aS.v, w1, accS[c], 0, 0, 0);
                accB[c] = __builtin_amdgcn_mfma_f32_16x16x32_bf16(aB.v, w2, accB[c], 0, 0, 0);
            }
        }

        // D mapping: col = lane&15 (=m), row = kg*4 + q
#pragma unroll
        for (int c = 0; c < 8; ++c) {
#pragma unroll
            for (int q = 0; q < 4; ++q) {
                int orow = wt * 16 + kg * 4 + q;
                out[(long long)orow * DD + c * 16 + m] =
                    lrelu(accS[c][q] + bs[c]) + lrelu(accB[c][q] + bb[c]);
            }
        }
    }
}

extern "C" void kernel_launch(void* const* d_in, const int* in_sizes, int n_in,
                              void* d_out, int out_size, void* d_ws, size_t ws_size,
                              hipStream_t stream)
{
    const float* ego = (const float*)d_in[0];
    const float* W1  = (const float*)d_in[16];
    const float* b1  = (const float*)d_in[17];
    const float* W2  = (const float*)d_in[18];
    const float* b2  = (const float*)d_in[19];

    BuildArgs a;
    a.rows[0] = (const int*)d_in[1];  a.cols[0] = (const int*)d_in[2];  a.vals[0] = (const float*)d_in[3];
    a.rows[1] = (const int*)d_in[4];  a.cols[1] = (const int*)d_in[5];  a.vals[1] = (const float*)d_in[6];
    a.rows[2] = (const int*)d_in[7];  a.cols[2] = (const int*)d_in[8];  a.vals[2] = (const float*)d_in[9];
    a.rows[3] = (const int*)d_in[10]; a.cols[3] = (const int*)d_in[11]; a.vals[3] = (const float*)d_in[12];
    a.rows[4] = (const int*)d_in[13]; a.cols[4] = (const int*)d_in[14]; a.vals[4] = (const float*)d_in[15];
    int nnz[5] = { in_sizes[1], in_sizes[4], in_sizes[7], in_sizes[10], in_sizes[13] };
    a.nnzbase[0] = 0;
    for (int s = 0; s < 5; ++s) a.nnzbase[s + 1] = a.nnzbase[s] + nnz[s];
    const int total = a.nnzbase[5];

    // ---- workspace carve (arena time-shares the side region; arena = 48.8 MB) ----
    char* p = (char*)d_ws;
    float*    side    = (float*)p;
    int2*     arena   = (int2*)p;         p += (size_t)N_ENT * DD * 4;       // 51.2 MB
    unsigned* xq      = (unsigned*)p;     p += (size_t)140032 * 32 * 4;      // 17.9 MB (int8 rows x 140K)
    float*    xs      = (float*)p;        p += (size_t)140032 * 4;           // 560 KB
    int2*     cv      = (int2*)p;         p += (size_t)total * 8;            // 44.8 MB
    int*      rp      = (int*)p;          p += 141056 * 4;
    int*      gcursor = (int*)p;          p += 1024 * 4;
    int*      bbase   = (int*)p;          p += 1024 * 4;

    // build
    hipMemsetAsync(gcursor, 0, NB * sizeof(int), stream);
    quant_ego_kernel<<<(N_ENT * 32 + 255) / 256, 256, 0, stream>>>(ego, xq, xs);
    const int nblk_part = (total + TILE - 1) / TILE;
    partition_kernel<<<nblk_part, 256, 0, stream>>>(a, gcursor, arena);
    bucket_scan_kernel<<<1, 512, 0, stream>>>(gcursor, bbase, rp);
    bucket_sort_kernel<<<NB, 256, 0, stream>>>(gcursor, bbase, arena, cv, rp);

    // spmm (arena region is dead from here; side reuses it)
    spmm_stage1_kernel<<<(2 * N_HE) / 4, 256, 0, stream>>>(rp, cv, xq, xs);
    spmm_stage2_kernel<<<N_ENT / 4, 256, 0, stream>>>(rp, cv, xq, xs, side);

    // dense epilogue (MFMA, 512-thread blocks)
    dense_mfma_kernel<<<782, 512, 0, stream>>>(ego, side, W1, b1, W2, b2, (float*)d_out);
}

// Round 17
// 308.350 us; speedup vs baseline: 1.0040x; 1.0040x over previous
//
#include <hip/hip_runtime.h>

#define N_ENT 100000
#define N_HE  20000
#define DD    128

// Unified x-space rows: ego 0..100000, h1 100000..120000, h2 120000..140000
#define XROW_H1 100000
#define XROW_H2 120000

// rp row spaces
#define RP_S2  0
#define RP_P1  100001
#define RP_L1  120002

// Bucket geometry:
// region 0 = S2 (A+P2+L2 merged): 196 buckets, stride 512, cap 19968
// region 1 = P1: 79 buckets, stride 256, cap 13824
// region 2 = L1: 79 buckets, stride 256, cap 13824
#define NB 354
#define TILE 3072
#define EPT  12   // entries per thread = TILE/256

typedef float f32x4 __attribute__((ext_vector_type(4)));
typedef short bf16x8 __attribute__((ext_vector_type(8)));

__device__ __forceinline__ int bucket_region(int b) {
    return (b < 196) ? 0 : (b < 275) ? 1 : 2;
}
__device__ __forceinline__ int reg_shift(int r)      { return r == 0 ? 9 : 8; }
__device__ __forceinline__ int reg_bucketbase(int r) { return r == 0 ? 0 : r == 1 ? 196 : 275; }
__device__ __forceinline__ int reg_cap(int r)        { return r == 0 ? 19968 : 13824; }
__device__ __forceinline__ long long reg_arenabase(int r) {
    return r == 0 ? 0LL : r == 1 ? 3913728LL : 5005824LL;   // 196*19968 ; +79*13824
}
__device__ __forceinline__ int reg_rpbase(int r)     { return r == 0 ? RP_S2 : r == 1 ? RP_P1 : RP_L1; }
__device__ __forceinline__ int reg_rows(int r)       { return r == 0 ? 100000 : 20000; }

__device__ __forceinline__ unsigned short f2bf(float f) {
    unsigned u = __float_as_uint(f);
    unsigned r = (u + 0x7fffu + ((u >> 16) & 1u)) >> 16;   // RNE
    return (unsigned short)r;
}
__device__ __forceinline__ unsigned pack_bf16(float a, float b) {
    return (unsigned)f2bf(a) | ((unsigned)f2bf(b) << 16);
}
__device__ __forceinline__ float lrelu(float x) { return x > 0.0f ? x : 0.01f * x; }
__device__ __forceinline__ float i8f(unsigned u, int b) {
    return (float)((int)(u << (24 - 8 * b)) >> 24);
}

// ---------------- ego fp32 -> block-scaled int8 rows of xall ----------------
__global__ __launch_bounds__(256) void quant_ego_kernel(
    const float* __restrict__ ego, unsigned* __restrict__ xq,
    float* __restrict__ xs)
{
    int row = (blockIdx.x * 256 + threadIdx.x) >> 5;
    if (row >= N_ENT) return;
    int l = threadIdx.x & 31;
    const float4 v = *(const float4*)(ego + (long long)row * DD + l * 4);
    float m = fmaxf(fmaxf(fabsf(v.x), fabsf(v.y)), fmaxf(fabsf(v.z), fabsf(v.w)));
    for (int d = 1; d < 32; d <<= 1) m = fmaxf(m, __shfl_xor(m, d, 32));
    float inv = (m > 0.0f) ? 127.0f / m : 0.0f;
    int q0 = __float2int_rn(v.x * inv);
    int q1 = __float2int_rn(v.y * inv);
    int q2 = __float2int_rn(v.z * inv);
    int q3 = __float2int_rn(v.w * inv);
    unsigned pk = (q0 & 255) | ((q1 & 255) << 8) | ((q2 & 255) << 16) | ((q3 & 255) << 24);
    xq[row * 32 + l] = pk;
    if (l == 0) xs[row] = m * (1.0f / 127.0f);
}

struct BuildArgs {
    const int*   rows[5];
    const int*   cols[5];
    const float* vals[5];
    int nnzbase[6];
};

// seg -> bucket mapping: {A,P1,P2,L1,L2}
__device__ __forceinline__ int seg_bbase(int s)  { return (s == 1) ? 196 : (s == 3) ? 275 : 0; }
__device__ __forceinline__ int seg_shift2(int s) { return (s == 1 || s == 3) ? 8 : 9; }
__device__ __forceinline__ int seg_colofs(int s) { return (s == 2) ? XROW_H1 : (s == 4) ? XROW_H2 : 0; }

__device__ __forceinline__ void seg_of(int i, const int* nnzbase, int& seg, int& li) {
    int s = 0;
    s += (i >= nnzbase[1]);
    s += (i >= nnzbase[2]);
    s += (i >= nnzbase[3]);
    s += (i >= nnzbase[4]);
    seg = s; li = i - nnzbase[s];
}

// ---------------- Phase A: LDS-binned partition into bucket arena ----------------
__global__ __launch_bounds__(256, 4) void partition_kernel(
    BuildArgs a, int* __restrict__ gcursor, int2* __restrict__ arena)
{
    __shared__ int2 staging[TILE];              // 24 KB
    __shared__ unsigned short posb[TILE];       // 6 KB
    __shared__ int  hist[NB];
    __shared__ int  excl[NB + 1];
    __shared__ int  cursor[NB];
    __shared__ int  gofs[NB];                   // gbase[b] - excl[b]

    const int t = threadIdx.x;
    const int tile_base = blockIdx.x * TILE;
    const int total = a.nnzbase[5];
    int tile_n = total - tile_base;
    if (tile_n > TILE) tile_n = TILE;
    if (tile_n <= 0) return;

    for (int i = t; i < NB; i += 256) hist[i] = 0;
    __syncthreads();

    // pass 1: read rows+cols+vals ONCE, histogram, cache everything in regs
    int   pk[EPT];
    int   pcol[EPT];
    float pval[EPT];
#pragma unroll
    for (int q = 0; q < EPT; ++q) {
        int j = t + q * 256;
        pk[q] = -1;
        if (j < tile_n) {
            int i = tile_base + j;
            int seg, li; seg_of(i, a.nnzbase, seg, li);
            int row = a.rows[seg][li];
            pcol[q] = a.cols[seg][li] + seg_colofs(seg);
            pval[q] = a.vals[seg][li];
            int sh = seg_shift2(seg);
            int b = seg_bbase(seg) + (row >> sh);
            pk[q] = (b << 9) | (row & ((1 << sh) - 1));
            atomicAdd(&hist[b], 1);
        }
    }
    __syncthreads();

    // wave 0: exclusive scan of hist -> excl
    if (t < 64) {
        int carry = 0;
        for (int base = 0; base < NB; base += 64) {
            int idx = base + t;
            int v = (idx < NB) ? hist[idx] : 0;
            int inc = v;
            for (int d = 1; d < 64; d <<= 1) {
                int u = __shfl_up(inc, d, 64);
                if (t >= d) inc += u;
            }
            if (idx < NB) excl[idx] = carry + inc - v;
            carry += __shfl(inc, 63, 64);
        }
        if (t == 0) excl[NB] = carry;
    }
    __syncthreads();

    // reserve global arena ranges; init cursors; fill posb (fused loop)
    for (int b = t; b < NB; b += 256) {
        int e  = excl[b];
        int hi = excl[b + 1];
        int c  = hi - e;
        int gb = (c > 0) ? atomicAdd(&gcursor[b], c) : 0;
        cursor[b] = e;
        gofs[b] = gb - e;
        for (int p = e; p < hi; ++p) posb[p] = (unsigned short)b;
    }
    __syncthreads();

    // pass 2: scatter from regs into LDS staging grouped by bucket
#pragma unroll
    for (int q = 0; q < EPT; ++q) {
        if (pk[q] >= 0) {
            int b  = pk[q] >> 9;
            int rl = pk[q] & 511;
            int pos = atomicAdd(&cursor[b], 1);
            staging[pos] = make_int2((rl << 18) | pcol[q], __float_as_int(pval[q]));
        }
    }
    __syncthreads();

    // flush: contiguous, position-ordered writes
    for (int p = t; p < tile_n; p += 256) {
        int b = posb[p];
        int reg = bucket_region(b);
        long long slot = reg_arenabase(reg) + (long long)(b - reg_bucketbase(reg)) * reg_cap(reg);
        arena[slot + gofs[b] + p] = staging[p];
    }
}

// ---------------- bucket-count exclusive scan (+rp sentinels) ----------------
__global__ __launch_bounds__(512) void bucket_scan_kernel(
    const int* __restrict__ gcursor, int* __restrict__ bbase, int* __restrict__ rp)
{
    __shared__ int tmp[512];
    int t = threadIdx.x;
    int v = (t < NB) ? gcursor[t] : 0;
    tmp[t] = v;
    __syncthreads();
    for (int d = 1; d < 512; d <<= 1) {
        int u = (t >= d) ? tmp[t - d] : 0;
        __syncthreads();
        tmp[t] += u;
        __syncthreads();
    }
    if (t < NB) bbase[t] = tmp[t] - v;
    // region sentinels
    if (t == 196) rp[RP_S2 + 100000] = tmp[t] - v;   // end of S2
    if (t == 275) rp[RP_P1 + 20000]  = tmp[t] - v;   // end of P1
    if (t == NB - 1) rp[RP_L1 + 20000] = tmp[t];     // total
}

// ---------------- Phase B: per-bucket counting sort -> final cv + rp ----------------
__global__ __launch_bounds__(256) void bucket_sort_kernel(
    const int* __restrict__ gcursor, const int* __restrict__ bbase,
    const int2* __restrict__ arena, int2* __restrict__ cv, int* __restrict__ rp)
{
    __shared__ int hist[512];
    __shared__ int excl[512];
    __shared__ int wsum[4];

    const int b = blockIdx.x;
    const int t = threadIdx.x;
    const int reg = bucket_region(b);
    const int sh = reg_shift(reg);
    const int stride = 1 << sh;
    const int lb = b - reg_bucketbase(reg);
    const int row_base_local = lb << sh;
    int nrows = reg_rows(reg) - row_base_local;
    if (nrows > stride) nrows = stride;
    const long long slot = reg_arenabase(reg) + (long long)lb * reg_cap(reg);
    const int count = gcursor[b];
    const int fbase = bbase[b];

    for (int i = t; i < 512; i += 256) hist[i] = 0;
    __syncthreads();

    for (int j = t; j < count; j += 256) {
        int key = arena[slot + j].x;
        atomicAdd(&hist[key >> 18], 1);
    }
    __syncthreads();

    // exclusive scan of 512 bins (2 per thread)
    {
        const int lane = t & 63, wave = t >> 6;
        int v0 = hist[t * 2], v1 = hist[t * 2 + 1];
        int s = v0 + v1;
        int inc = s;
        for (int d = 1; d < 64; d <<= 1) {
            int u = __shfl_up(inc, d, 64);
            if (lane >= d) inc += u;
        }
        if (lane == 63) wsum[wave] = inc;
        __syncthreads();
        int woff = 0;
        for (int w = 0; w < wave; ++w) woff += wsum[w];
        int run = woff + inc - s;
        excl[t * 2] = run;
        excl[t * 2 + 1] = run + v0;
    }
    __syncthreads();

    const int grow0 = reg_rpbase(reg) + row_base_local;
    for (int r = t; r < nrows; r += 256)
        rp[grow0 + r] = fbase + excl[r];
    __syncthreads();

    for (int j = t; j < count; j += 256) {
        int2 e = arena[slot + j];
        int r = e.x >> 18;
        int pos = atomicAdd(&excl[r], 1);
        cv[fbase + pos] = make_int2(e.x & 0x3FFFF, e.y);
    }
}

// ---------------- SpMM gather walk: group-of-8, depth-2 software pipeline ----------------
// Lane l: group g = l>>3 handles nnz; sublane s = l&7 loads 16 B of the row.
// Each iteration covers 16 nnz with TWO independent uint4 loads issued
// back-to-back (named regs, no runtime indexing) -> 2 gathers in flight/wave.
// Tail handled by index-clamp (duplicate line loads, vs=0).
__device__ __forceinline__ void walk_row8(
    const int2* __restrict__ cv, int start, int end, int lane,
    const unsigned* __restrict__ xq, const float* __restrict__ xs, float* acc)
{
    const int g  = lane >> 3;
    const int s4 = (lane & 7) * 4;

    for (int sb = start; sb < end; sb += 64) {
        int nn = end - sb; if (nn > 64) nn = 64;
        int2 mycv = make_int2(0, 0);
        float myv = 0.0f;
        if (lane < nn) {
            mycv = cv[sb + lane];
            myv = __int_as_float(mycv.y) * xs[mycv.x];
        }
        const int nn1 = nn - 1;
        for (int jb = 0; jb < nn; jb += 16) {
            int idx0 = jb + g;
            int idx1 = jb + 8 + g;
            int i0 = idx0 < nn1 ? idx0 : nn1;
            int i1 = idx1 < nn1 ? idx1 : nn1;
            int   cs0 = __shfl(mycv.x, i0, 64);
            int   cs1 = __shfl(mycv.x, i1, 64);
            float vs0 = __shfl(myv, i0, 64);
            float vs1 = __shfl(myv, i1, 64);
            vs0 = (idx0 <= nn1) ? vs0 : 0.0f;
            vs1 = (idx1 <= nn1) ? vs1 : 0.0f;
            // issue both loads before any compute
            const uint4 u0 = *reinterpret_cast<const uint4*>(xq + cs0 * 32 + s4);
            const uint4 u1 = *reinterpret_cast<const uint4*>(xq + cs1 * 32 + s4);
#pragma unroll
            for (int w = 0; w < 4; ++w) {
                unsigned uw = (&u0.x)[w];
                acc[w * 4 + 0] = fmaf(vs0, i8f(uw, 0), acc[w * 4 + 0]);
                acc[w * 4 + 1] = fmaf(vs0, i8f(uw, 1), acc[w * 4 + 1]);
                acc[w * 4 + 2] = fmaf(vs0, i8f(uw, 2), acc[w * 4 + 2]);
                acc[w * 4 + 3] = fmaf(vs0, i8f(uw, 3), acc[w * 4 + 3]);
            }
#pragma unroll
            for (int w = 0; w < 4; ++w) {
                unsigned uw = (&u1.x)[w];
                acc[w * 4 + 0] = fmaf(vs1, i8f(uw, 0), acc[w * 4 + 0]);
                acc[w * 4 + 1] = fmaf(vs1, i8f(uw, 1), acc[w * 4 + 1]);
                acc[w * 4 + 2] = fmaf(vs1, i8f(uw, 2), acc[w * 4 + 2]);
                acc[w * 4 + 3] = fmaf(vs1, i8f(uw, 3), acc[w * 4 + 3]);
            }
        }
    }
}

__device__ __forceinline__ void reduce_groups8(float* acc)
{
#pragma unroll
    for (int e = 0; e < 16; ++e) {
        acc[e] += __shfl_xor(acc[e], 8, 64);
        acc[e] += __shfl_xor(acc[e], 16, 64);
        acc[e] += __shfl_xor(acc[e], 32, 64);
    }
}

// stage 1: h1 = p1 @ ego, h2 = l1 @ ego  (int8 gather -> int8 block-scaled rows of xall)
__global__ __launch_bounds__(256) void spmm_stage1_kernel(
    const int* __restrict__ rp, const int2* __restrict__ cv,
    unsigned* __restrict__ xq, float* __restrict__ xs)
{
    int wid = (blockIdx.x * 256 + threadIdx.x) >> 6;
    int lane = threadIdx.x & 63;
    if (wid >= 2 * N_HE) return;
    int rbase, xrow;
    if (wid < N_HE) { rbase = RP_P1 + wid;           xrow = XROW_H1 + wid; }
    else            { rbase = RP_L1 + (wid - N_HE);  xrow = XROW_H2 + (wid - N_HE); }

    float acc[16];
#pragma unroll
    for (int e = 0; e < 16; ++e) acc[e] = 0.0f;
    walk_row8(cv, rp[rbase], rp[rbase + 1], lane, xq, xs, acc);
    reduce_groups8(acc);

    float m = 0.0f;
#pragma unroll
    for (int e = 0; e < 16; ++e) m = fmaxf(m, fabsf(acc[e]));
    m = fmaxf(m, __shfl_xor(m, 1, 64));
    m = fmaxf(m, __shfl_xor(m, 2, 64));
    m = fmaxf(m, __shfl_xor(m, 4, 64));
    float inv = (m > 0.0f) ? 127.0f / m : 0.0f;

    if (lane < 8) {
        uint4 o;
#pragma unroll
        for (int w = 0; w < 4; ++w) {
            int q0 = __float2int_rn(acc[w * 4 + 0] * inv);
            int q1 = __float2int_rn(acc[w * 4 + 1] * inv);
            int q2 = __float2int_rn(acc[w * 4 + 2] * inv);
            int q3 = __float2int_rn(acc[w * 4 + 3] * inv);
            (&o.x)[w] = (q0 & 255) | ((q1 & 255) << 8) | ((q2 & 255) << 16) | ((q3 & 255) << 24);
        }
        *reinterpret_cast<uint4*>(xq + xrow * 32 + lane * 4) = o;
        if (lane == 0) xs[xrow] = m * (1.0f / 127.0f);
    }
}

// stage 2: side = (A|p2|l2) @ xall  — ONE merged walk per output row
__global__ __launch_bounds__(256) void spmm_stage2_kernel(
    const int* __restrict__ rp, const int2* __restrict__ cv,
    const unsigned* __restrict__ xq, const float* __restrict__ xs,
    float* __restrict__ side)
{
    int wid = (blockIdx.x * 256 + threadIdx.x) >> 6;
    int lane = threadIdx.x & 63;
    if (wid >= N_ENT) return;

    float acc[16];
#pragma unroll
    for (int e = 0; e < 16; ++e) acc[e] = 0.0f;
    walk_row8(cv, rp[wid], rp[wid + 1], lane, xq, xs, acc);
    reduce_groups8(acc);

    if (lane < 8) {
        float* yp = side + (long long)wid * DD + lane * 16;
#pragma unroll
        for (int w = 0; w < 4; ++w)
            *reinterpret_cast<float4*>(yp + w * 4) =
                make_float4(acc[w * 4], acc[w * 4 + 1], acc[w * 4 + 2], acc[w * 4 + 3]);
    }
}

// ---------------- MFMA dense epilogue (512 threads, 16 rows/wave) ----------------
union BfFrag { unsigned u[4]; bf16x8 v; };

__global__ __launch_bounds__(512, 4) void dense_mfma_kernel(
    const float* __restrict__ ego, const float* __restrict__ side,
    const float* __restrict__ W1, const float* __restrict__ b1,
    const float* __restrict__ W2, const float* __restrict__ b2,
    float* __restrict__ out)
{
    __shared__ unsigned Wb1[8192];   // 32 KB: W1 bf16, swizzled
    __shared__ unsigned Wb2[8192];   // 32 KB: W2 bf16, swizzled

    const int tid = threadIdx.x;

    for (int idx = tid; idx < 8192; idx += 512) {
        int row = idx >> 6, pc = idx & 63;
        unsigned pk1 = pack_bf16(W1[row * 128 + pc * 2], W1[row * 128 + pc * 2 + 1]);
        unsigned pk2 = pack_bf16(W2[row * 128 + pc * 2], W2[row * 128 + pc * 2 + 1]);
        int boff = row * 256 + ((pc * 4) ^ ((row & 7) << 4));
        *(unsigned*)((char*)Wb1 + boff) = pk1;
        *(unsigned*)((char*)Wb2 + boff) = pk2;
    }
    __syncthreads();

    const int wave = tid >> 6;   // 0..7
    const int lane = tid & 63;
    const int m    = lane & 15;
    const int kg   = lane >> 4;

    float bs[8], bb[8];
#pragma unroll
    for (int c = 0; c < 8; ++c) {
        bs[c] = b1[c * 16 + m];
        bb[c] = b2[c * 16 + m];
    }

    for (int wt = blockIdx.x * 8 + wave; wt < 6250; wt += gridDim.x * 8) {
        const long long r0 = (long long)(wt * 16 + m) * DD;

        f32x4 accS[8], accB[8];
#pragma unroll
        for (int c = 0; c < 8; ++c) { accS[c] = (f32x4)0.0f; accB[c] = (f32x4)0.0f; }

#pragma unroll 1
        for (int kk = 0; kk < 4; ++kk) {
            const int kb = kk * 32 + kg * 8;

            float4 ea = *(const float4*)(ego  + r0 + kb);
            float4 eb = *(const float4*)(ego  + r0 + kb + 4);
            float4 sa = *(const float4*)(side + r0 + kb);
            float4 sb = *(const float4*)(side + r0 + kb + 4);

            BfFrag aS, aB;
            aS.u[0] = pack_bf16(ea.x + sa.x, ea.y + sa.y);
            aS.u[1] = pack_bf16(ea.z + sa.z, ea.w + sa.w);
            aS.u[2] = pack_bf16(eb.x + sb.x, eb.y + sb.y);
            aS.u[3] = pack_bf16(eb.z + sb.z, eb.w + sb.w);
            aB.u[0] = pack_bf16(ea.x * sa.x, ea.y * sa.y);
            aB.u[1] = pack_bf16(ea.z * sa.z, ea.w * sa.w);
            aB.u[2] = pack_bf16(eb.x * sb.x, eb.y * sb.y);
            aB.u[3] = pack_bf16(eb.z * sb.z, eb.w * sb.w);

#pragma unroll
            for (int c = 0; c < 8; ++c) {
                int wrow = c * 16 + m;
                int boff = wrow * 256 + ((kk * 64 + (kg << 4)) ^ ((wrow & 7) << 4));
                bf16x8 w1 = *(const bf16x8*)((const char*)Wb1 + boff);
                bf16x8 w2 = *(const bf16x8*)((const char*)Wb2 + boff);
                accS[c] = __builtin_amdgcn_mfma_f32_16x16x32_bf16(aS.v, w1, accS[c], 0, 0, 0);
                accB[c] = __builtin_amdgcn_mfma_f32_16x16x32_bf16(aB.v, w2, accB[c], 0, 0, 0);
            }
        }

        // D mapping: col = lane&15 (=m), row = kg*4 + q
#pragma unroll
        for (int c = 0; c < 8; ++c) {
#pragma unroll
            for (int q = 0; q < 4; ++q) {
                int orow = wt * 16 + kg * 4 + q;
                out[(long long)orow * DD + c * 16 + m] =
                    lrelu(accS[c][q] + bs[c]) + lrelu(accB[c][q] + bb[c]);
            }
        }
    }
}

extern "C" void kernel_launch(void* const* d_in, const int* in_sizes, int n_in,
                              void* d_out, int out_size, void* d_ws, size_t ws_size,
                              hipStream_t stream)
{
    const float* ego = (const float*)d_in[0];
    const float* W1  = (const float*)d_in[16];
    const float* b1  = (const float*)d_in[17];
    const float* W2  = (const float*)d_in[18];
    const float* b2  = (const float*)d_in[19];

    BuildArgs a;
    a.rows[0] = (const int*)d_in[1];  a.cols[0] = (const int*)d_in[2];  a.vals[0] = (const float*)d_in[3];
    a.rows[1] = (const int*)d_in[4];  a.cols[1] = (const int*)d_in[5];  a.vals[1] = (const float*)d_in[6];
    a.rows[2] = (const int*)d_in[7];  a.cols[2] = (const int*)d_in[8];  a.vals[2] = (const float*)d_in[9];
    a.rows[3] = (const int*)d_in[10]; a.cols[3] = (const int*)d_in[11]; a.vals[3] = (const float*)d_in[12];
    a.rows[4] = (const int*)d_in[13]; a.cols[4] = (const int*)d_in[14]; a.vals[4] = (const float*)d_in[15];
    int nnz[5] = { in_sizes[1], in_sizes[4], in_sizes[7], in_sizes[10], in_sizes[13] };
    a.nnzbase[0] = 0;
    for (int s = 0; s < 5; ++s) a.nnzbase[s + 1] = a.nnzbase[s] + nnz[s];
    const int total = a.nnzbase[5];

    // ---- workspace carve (arena time-shares the side region; arena = 48.8 MB) ----
    char* p = (char*)d_ws;
    float*    side    = (float*)p;
    int2*     arena   = (int2*)p;         p += (size_t)N_ENT * DD * 4;       // 51.2 MB
    unsigned* xq      = (unsigned*)p;     p += (size_t)140032 * 32 * 4;      // 17.9 MB (int8 rows x 140K)
    float*    xs      = (float*)p;        p += (size_t)140032 * 4;           // 560 KB
    int2*     cv      = (int2*)p;         p += (size_t)total * 8;            // 44.8 MB
    int*      rp      = (int*)p;          p += 141056 * 4;
    int*      gcursor = (int*)p;          p += 1024 * 4;
    int*      bbase   = (int*)p;          p += 1024 * 4;

    // build
    hipMemsetAsync(gcursor, 0, NB * sizeof(int), stream);
    quant_ego_kernel<<<(N_ENT * 32 + 255) / 256, 256, 0, stream>>>(ego, xq, xs);
    const int nblk_part = (total + TILE - 1) / TILE;
    partition_kernel<<<nblk_part, 256, 0, stream>>>(a, gcursor, arena);
    bucket_scan_kernel<<<1, 512, 0, stream>>>(gcursor, bbase, rp);
    bucket_sort_kernel<<<NB, 256, 0, stream>>>(gcursor, bbase, arena, cv, rp);

    // spmm (arena region is dead from here; side reuses it)
    spmm_stage1_kernel<<<(2 * N_HE) / 4, 256, 0, stream>>>(rp, cv, xq, xs);
    spmm_stage2_kernel<<<N_ENT / 4, 256, 0, stream>>>(rp, cv, xq, xs, side);

    // dense epilogue (MFMA, 512-thread blocks)
    dense_mfma_kernel<<<782, 512, 0, stream>>>(ego, side, W1, b1, W2, b2, (float*)d_out);
}